// Round 5
// baseline (133.764 us; speedup 1.0000x reference)
//
#include <hip/hip_runtime.h>

typedef unsigned int uint;
typedef _Float16 f16;

typedef __attribute__((ext_vector_type(8))) _Float16 f16x8;
typedef __attribute__((ext_vector_type(2))) _Float16 f16x2;
typedef __attribute__((ext_vector_type(4))) float f32x4;

#define E_CNT 496

// W2 f16 image: [96][264] f16 = 50688 B. Row stride 264 f16 = 132 dwords
// (132 mod 32 = 4 -> quarter-wave b128 frag reads are 2-way = free).
#define W2_STRIDE 264
#define W2_STAGE_BYTES 52224             // 51 x 1024 (pad past 50688)
#define W2_CHUNKS 51
#define LDS_BYTES 52224

// payoff per-wave overlay region: [2 sides][8 pp][136 f16] = 2176 f16 = 4352 B
#define PP_STRIDE 136
#define V_OFF 1088
#define PW_F16 2176

// x_kernel LDS: float hidden image 64x132 (33792 B) overlaid later by
// f16 X slab 64x136 (17408 B)
#define XK_LDS_BYTES 33792
#define XS_STRIDE 136

__device__ __forceinline__ uint pack2_f16(float lo, float hi) {
    union { f16x2 h; uint u; } r;
    r.h[0] = (_Float16)lo;
    r.h[1] = (_Float16)hi;
    return r.u;
}

__device__ __forceinline__ void load_lds16(const void* g, void* l) {
    __builtin_amdgcn_global_load_lds(
        (const __attribute__((address_space(1))) void*)g,
        (__attribute__((address_space(3))) void*)l, 16, 0, 0);
}

// ---------------- X staging via swapped-operand MFMA; W1 frags in registers --
// grid = 513; blocks 0..511 = 128 rowblocks x 4 ngroups; block 512 converts W2.
// All acc tiles kept in regs; single LDS dump -> coalesced 16B global stores.
__global__ __launch_bounds__(256) void x_kernel(
    const float* __restrict__ hidden, const float* __restrict__ W1,
    const float* __restrict__ b1, f16* __restrict__ Xout,
    const float* __restrict__ W2, f16* __restrict__ w2h) {
    __shared__ __align__(16) unsigned char xsmem[XK_LDS_BYTES];
    float* hs = (float*)xsmem;          // phase 1: hidden [64][132] f32
    f16* xs = (f16*)xsmem;              // phase 2: X slab [64][136] f16

    const int tid = threadIdx.x;

    if (blockIdx.x == 512) {
        // convert W2 f32 [96][256] -> f16 image [96][264] (pad never read)
        #pragma unroll
        for (int j = 0; j < 24; ++j) {
            int idx4 = tid + j * 256;       // float4 index 0..6143
            int n = idx4 >> 6;
            int k = (idx4 & 63) << 2;
            float4 v = *(const float4*)&W2[n * 256 + k];
            uint2 o;
            o.x = pack2_f16(v.x, v.y);
            o.y = pack2_f16(v.z, v.w);
            *(uint2*)&w2h[n * W2_STRIDE + k] = o;
        }
        return;
    }

    const int rowblock = blockIdx.x >> 2;
    const int g = blockIdx.x & 3;
    const int ln = tid & 63;
    const int waveId = tid >> 6;
    const int quad = ln >> 4;
    const int l16 = ln & 15;
    const int row0 = rowblock * 64;
    const int half = g >> 1;            // block covers h-slab [128*(g&1), +128) of this half
    const int hbase = (g & 1) * 128;

    union FU { uint u[4]; f16x8 v; };
    FU wf[2][4];
    float bh[2][4];
    #pragma unroll
    for (int nt = 0; nt < 2; ++nt) {
        const int t = (g * 4 + waveId) * 2 + nt;   // global ntile; local = 2*waveId+nt
        const int htile = t & 15;
        const float* wrow = W1 + (htile * 16 + l16) * 256 + half * 128 + quad * 8;
        #pragma unroll
        for (int kk = 0; kk < 4; ++kk) {
            float4 v0 = *(const float4*)(wrow + kk * 32);
            float4 v1 = *(const float4*)(wrow + kk * 32 + 4);
            wf[nt][kk].u[0] = pack2_f16(v0.x, v0.y);
            wf[nt][kk].u[1] = pack2_f16(v0.z, v0.w);
            wf[nt][kk].u[2] = pack2_f16(v1.x, v1.y);
            wf[nt][kk].u[3] = pack2_f16(v1.z, v1.w);
        }
        #pragma unroll
        for (int r = 0; r < 4; ++r)
            bh[nt][r] = 0.5f * b1[htile * 16 + quad * 4 + r];  // each half adds 0.5*b1
    }

    {
        const float* src = hidden + row0 * 128;
        #pragma unroll
        for (int it = 0; it < 8; ++it) {
            int idx = it * 256 + tid;
            int r = idx >> 5;
            int c4 = idx & 31;
            float4 v = *(const float4*)(src + idx * 4);
            *(float4*)&hs[r * 132 + c4 * 4] = v;
        }
    }
    __syncthreads();

    f32x4 accs[4][2];
    #pragma unroll
    for (int ch = 0; ch < 4; ++ch) {
        FU hf[4];
        const float* hrow = &hs[(ch * 16 + l16) * 132 + quad * 8];
        #pragma unroll
        for (int kk = 0; kk < 4; ++kk) {
            float4 v0 = *(const float4*)(hrow + kk * 32);
            float4 v1 = *(const float4*)(hrow + kk * 32 + 4);
            hf[kk].u[0] = pack2_f16(v0.x, v0.y);
            hf[kk].u[1] = pack2_f16(v0.z, v0.w);
            hf[kk].u[2] = pack2_f16(v1.x, v1.y);
            hf[kk].u[3] = pack2_f16(v1.z, v1.w);
        }
        #pragma unroll
        for (int nt = 0; nt < 2; ++nt) {
            f32x4 acc = (f32x4){0.f, 0.f, 0.f, 0.f};
            #pragma unroll
            for (int kk = 0; kk < 4; ++kk)
                acc = __builtin_amdgcn_mfma_f32_16x16x32_f16(wf[nt][kk].v, hf[kk].v, acc, 0, 0, 0);
            accs[ch][nt] = acc;
        }
    }

    __syncthreads();   // all hidden LDS reads done; overlay f16 X slab

    // dump accs (+bias, f16) into [row 64][hloc 128] slab, stride 136
    #pragma unroll
    for (int ch = 0; ch < 4; ++ch) {
        #pragma unroll
        for (int nt = 0; nt < 2; ++nt) {
            uint2 o;
            o.x = pack2_f16(accs[ch][nt][0] + bh[nt][0], accs[ch][nt][1] + bh[nt][1]);
            o.y = pack2_f16(accs[ch][nt][2] + bh[nt][2], accs[ch][nt][3] + bh[nt][3]);
            *(uint2*)&xs[(ch * 16 + l16) * XS_STRIDE + (2 * waveId + nt) * 16 + quad * 4] = o;
        }
    }

    __syncthreads();

    // coalesced readout: 1024 b128 chunks; lane i -> 16B, 256B/row segments
    f16* xdst = Xout + half * (8192 * 256) + row0 * 256 + hbase;
    #pragma unroll
    for (int it = 0; it < 4; ++it) {
        int idx = it * 256 + tid;       // 0..1023
        int row = idx >> 4;
        int h8 = idx & 15;
        uint4 v = *(const uint4*)&xs[row * XS_STRIDE + h8 * 8];
        *(uint4*)&xdst[row * 256 + h8 * 8] = v;
    }
}

// ---------------- fused GEMM2 (MFMA, fp16) + MFMA payoff ----------------
// block = 512 thr = 8 waves; each wave owns 16 pairs (2 chunks of 8);
// 128 pairs/block; grid 992 XCD-swizzled. W2 staged ONCE; each W2 LDS
// fragment read feeds BOTH chunks (halves W2 ds_read per pair).
__global__ __launch_bounds__(512) void gemm_payoff_kernel(
    const f16* __restrict__ X1, const f16* __restrict__ X2,
    const int* __restrict__ e_f, const int* __restrict__ e_t,
    const f16* __restrict__ w2g, const float* __restrict__ b2,
    float* __restrict__ out) {

    __shared__ __align__(16) unsigned char smem[LDS_BYTES];
    f16* w2s = (f16*)smem;

    const int tid = threadIdx.x;
    const int ln = tid & 63;
    const int waveId = tid >> 6;
    const int quad = ln >> 4;
    const int l16 = ln & 15;
    const int pl = l16 & 7;
    const int s = l16 >> 3;

    // XCD swizzle: 992 = 8 * 124 (bijective)
    const int bx = blockIdx.x;
    const int lb = (bx & 7) * 124 + (bx >> 3);

    // stage full W2 image once: 51 x 1KB async chunks, wave-strided
    {
        const unsigned char* src = (const unsigned char*)w2g + ln * 16;
        #pragma unroll
        for (int j = 0; j < 7; ++j) {
            int i = waveId + j * 8;
            if (i < W2_CHUNKS)
                load_lds16(src + i * 1024, smem + i * 1024);
        }
    }

    // edge dtype detect (uniform -> scalar loads)
    bool f64 = true, t64 = true;
    #pragma unroll
    for (int i = 0; i < 16; ++i) {
        if (e_f[2 * i + 1] != 0) f64 = false;
        if (e_t[2 * i + 1] != 0) t64 = false;
    }

    const int pairBase = lb * 128 + waveId * 16;
    const f16* px1[2];
    const f16* px2[2];
    #pragma unroll
    for (int c = 0; c < 2; ++c) {
        int pair = pairBase + c * 8 + pl;
        int b = pair / E_CNT;
        int e = pair - b * E_CNT;
        int f = f64 ? e_f[2 * e] : e_f[e];
        int t = t64 ? e_t[2 * e] : e_t[e];
        int n1 = s ? t : f;
        int n2 = s ? f : t;
        px1[c] = X1 + ((b * 32 + n1) * 256 + quad * 8);
        px2[c] = X2 + ((b * 32 + n2) * 256 + quad * 8);
    }

    f32x4 acc[2][6];
    #pragma unroll
    for (int c = 0; c < 2; ++c)
        #pragma unroll
        for (int tt = 0; tt < 6; ++tt) acc[c][tt] = (f32x4){0.f, 0.f, 0.f, 0.f};

    typedef union { uint4 q; f16x8 h; } XU;
    XU G1[2][2], G2[2][2];  // [buf][chunk]
    #pragma unroll
    for (int c = 0; c < 2; ++c) {
        G1[0][c].q = *(const uint4*)(px1[c] + 0 * 32);
        G2[0][c].q = *(const uint4*)(px2[c] + 0 * 32);
        G1[1][c].q = *(const uint4*)(px1[c] + 1 * 32);
        G2[1][c].q = *(const uint4*)(px2[c] + 1 * 32);
    }

    const f16x8 zero8 = (f16x8){0, 0, 0, 0, 0, 0, 0, 0};

    __syncthreads();   // W2 fully staged

    // all 8 kk, no internal barriers; each W2 frag read serves both chunks
    #pragma unroll
    for (int kk = 0; kk < 8; ++kk) {
        const int buf = kk & 1;
        f16x8 af[2];
        #pragma unroll
        for (int c = 0; c < 2; ++c) {
            f16x8 sum = G1[buf][c].h + G2[buf][c].h;
            af[c] = __builtin_elementwise_max(sum, zero8);
        }
        if (kk < 6) {
            #pragma unroll
            for (int c = 0; c < 2; ++c) {
                G1[buf][c].q = *(const uint4*)(px1[c] + (kk + 2) * 32);
                G2[buf][c].q = *(const uint4*)(px2[c] + (kk + 2) * 32);
            }
        }
        #pragma unroll
        for (int tt = 0; tt < 6; ++tt) {
            f16x8 bf = *(const f16x8*)&w2s[(tt * 16 + l16) * W2_STRIDE + kk * 32 + quad * 8];
            acc[0][tt] = __builtin_amdgcn_mfma_f32_16x16x32_f16(af[0], bf, acc[0][tt], 0, 0, 0);
            acc[1][tt] = __builtin_amdgcn_mfma_f32_16x16x32_f16(af[1], bf, acc[1][tt], 0, 0, 0);
        }
    }

    // epilogue precompute AFTER the K-loop (keeps K-loop peak registers low)
    float b2v[6];
    #pragma unroll
    for (int tt = 0; tt < 6; ++tt) b2v[tt] = b2[tt * 16 + l16];

    int d6[6];
    float psc[6];
    {
        const int s_ = quad >> 1;
        #pragma unroll
        for (int tt = 0; tt < 6; ++tt) {
            int n = tt * 16 + l16;
            int rr = n / 24;
            int rem = n - rr * 24;
            int c01 = (rem >= 12) ? 1 : 0;
            int a = rem - c01 * 12;
            int k8 = s_ * 4 + rr;
            int toL = (c01 == s_) ? 1 : 0;
            d6[tt] = (toL ? 0 : V_OFF) + (quad & 1) * 4 * PP_STRIDE + a * 8 + k8;
            psc[tt] = toL ? 0.5f : 1.0f;   // fold the 0.5 into the U (left) side
        }
    }

    __syncthreads();   // all waves done reading W2; overlay per-wave payoff regions

    f16* pm = (f16*)smem + waveId * PW_F16;

    #pragma unroll
    for (int c = 0; c < 2; ++c) {
        // dump p (+b2, x psc) as f16 into [side][pp][i*8+k8], pp-stride 136
        #pragma unroll
        for (int tt = 0; tt < 6; ++tt) {
            #pragma unroll
            for (int r = 0; r < 4; ++r)
                pm[d6[tt] + r * PP_STRIDE] = (_Float16)((acc[c][tt][r] + b2v[tt]) * psc[tt]);
        }

        // payoff: one MFMA per pair, A = V (j rows), B = U (i rows)
        // -> D[col=l16=i][row=quad*4+r=j] -> coalesced float4 stores
        #pragma unroll
        for (int pp = 0; pp < 8; ++pp) {
            f16x8 afp = zero8, bfp = zero8;
            if (quad == 0) {
                afp = *(const f16x8*)&pm[V_OFF + pp * PP_STRIDE + l16 * 8];
                bfp = *(const f16x8*)&pm[pp * PP_STRIDE + l16 * 8];
            }
            f32x4 d = __builtin_amdgcn_mfma_f32_16x16x32_f16(
                afp, bfp, (f32x4){0.f, 0.f, 0.f, 0.f}, 0, 0, 0);
            if (l16 < 12 && quad < 3) {
                float* ob = out + (pairBase + c * 8 + pp) * 144 + l16 * 12 + quad * 4;
                *(float4*)ob = make_float4(d[0], d[1], d[2], d[3]);
            }
        }
        // per-wave region reused for c=1; same-wave LDS ops are in-order
    }
}

extern "C" void kernel_launch(void* const* d_in, const int* in_sizes, int n_in,
                              void* d_out, int out_size, void* d_ws, size_t ws_size,
                              hipStream_t stream) {
    const float* hidden = (const float*)d_in[0];
    const float* W1 = (const float*)d_in[1];
    const float* b1 = (const float*)d_in[2];
    const float* W2 = (const float*)d_in[3];
    const float* b2 = (const float*)d_in[4];
    const int* e_f = (const int*)d_in[5];
    const int* e_t = (const int*)d_in[6];
    float* out = (float*)d_out;

    char* ws = (char*)d_ws;
    f16* X = (f16*)ws;                              // X1 then X2, 4 MB each
    f16* w2h = (f16*)(ws + 8 * 1024 * 1024);        // W2 f16 image [96][264] + stage slop

    x_kernel<<<513, 256, 0, stream>>>(hidden, W1, b1, X, W2, w2h);
    gemm_payoff_kernel<<<992, 512, 0, stream>>>(X, X + 8192 * 256, e_f, e_t, w2h, b2, out);
}

// Round 6
// 132.202 us; speedup vs baseline: 1.0118x; 1.0118x over previous
//
#include <hip/hip_runtime.h>

typedef unsigned int uint;
typedef _Float16 f16;

typedef __attribute__((ext_vector_type(8))) _Float16 f16x8;
typedef __attribute__((ext_vector_type(2))) _Float16 f16x2;
typedef __attribute__((ext_vector_type(4))) float f32x4;

#define E_CNT 496

// W2 f16 image: [96][264] f16 = 50688 B. Row stride 264 f16 = 132 dwords
// (132 mod 32 = 4 -> quarter-wave b128 frag reads spread banks; balanced).
#define W2_STRIDE 264
#define W2_STAGE_BYTES 52224             // 51 x 1024 (pad past 50688)
#define W2_CHUNKS 51
#define LDS_BYTES 52224

// payoff per-wave overlay region: [2 sides][8 pp][136 f16] = 2176 f16 = 4352 B
#define PP_STRIDE 136
#define V_OFF 1088
#define PW_F16 2176

// x_kernel LDS: float hidden image 64x132 (33792 B) overlaid later by
// f16 X slab 64x136 (17408 B)
#define XK_LDS_BYTES 33792
#define XS_STRIDE 136

__device__ __forceinline__ uint pack2_f16(float lo, float hi) {
    union { f16x2 h; uint u; } r;
    r.h[0] = (_Float16)lo;
    r.h[1] = (_Float16)hi;
    return r.u;
}

__device__ __forceinline__ void load_lds16(const void* g, void* l) {
    __builtin_amdgcn_global_load_lds(
        (const __attribute__((address_space(1))) void*)g,
        (__attribute__((address_space(3))) void*)l, 16, 0, 0);
}

// ---------------- X staging via swapped-operand MFMA; W1 frags in registers --
// grid = 513; blocks 0..511 = 128 rowblocks x 4 ngroups; block 512 converts W2.
// All acc tiles kept in regs; single LDS dump -> coalesced 16B global stores.
__global__ __launch_bounds__(256) void x_kernel(
    const float* __restrict__ hidden, const float* __restrict__ W1,
    const float* __restrict__ b1, f16* __restrict__ Xout,
    const float* __restrict__ W2, f16* __restrict__ w2h) {
    __shared__ __align__(16) unsigned char xsmem[XK_LDS_BYTES];
    float* hs = (float*)xsmem;          // phase 1: hidden [64][132] f32
    f16* xs = (f16*)xsmem;              // phase 2: X slab [64][136] f16

    const int tid = threadIdx.x;

    if (blockIdx.x == 512) {
        // convert W2 f32 [96][256] -> f16 image [96][264] (pad never read)
        #pragma unroll
        for (int j = 0; j < 24; ++j) {
            int idx4 = tid + j * 256;       // float4 index 0..6143
            int n = idx4 >> 6;
            int k = (idx4 & 63) << 2;
            float4 v = *(const float4*)&W2[n * 256 + k];
            uint2 o;
            o.x = pack2_f16(v.x, v.y);
            o.y = pack2_f16(v.z, v.w);
            *(uint2*)&w2h[n * W2_STRIDE + k] = o;
        }
        return;
    }

    const int rowblock = blockIdx.x >> 2;
    const int g = blockIdx.x & 3;
    const int ln = tid & 63;
    const int waveId = tid >> 6;
    const int quad = ln >> 4;
    const int l16 = ln & 15;
    const int row0 = rowblock * 64;
    const int half = g >> 1;            // block covers h-slab [128*(g&1), +128) of this half
    const int hbase = (g & 1) * 128;

    union FU { uint u[4]; f16x8 v; };
    FU wf[2][4];
    float bh[2][4];
    #pragma unroll
    for (int nt = 0; nt < 2; ++nt) {
        const int t = (g * 4 + waveId) * 2 + nt;   // global ntile; local = 2*waveId+nt
        const int htile = t & 15;
        const float* wrow = W1 + (htile * 16 + l16) * 256 + half * 128 + quad * 8;
        #pragma unroll
        for (int kk = 0; kk < 4; ++kk) {
            float4 v0 = *(const float4*)(wrow + kk * 32);
            float4 v1 = *(const float4*)(wrow + kk * 32 + 4);
            wf[nt][kk].u[0] = pack2_f16(v0.x, v0.y);
            wf[nt][kk].u[1] = pack2_f16(v0.z, v0.w);
            wf[nt][kk].u[2] = pack2_f16(v1.x, v1.y);
            wf[nt][kk].u[3] = pack2_f16(v1.z, v1.w);
        }
        #pragma unroll
        for (int r = 0; r < 4; ++r)
            bh[nt][r] = 0.5f * b1[htile * 16 + quad * 4 + r];  // each half adds 0.5*b1
    }

    {
        const float* src = hidden + row0 * 128;
        #pragma unroll
        for (int it = 0; it < 8; ++it) {
            int idx = it * 256 + tid;
            int r = idx >> 5;
            int c4 = idx & 31;
            float4 v = *(const float4*)(src + idx * 4);
            *(float4*)&hs[r * 132 + c4 * 4] = v;
        }
    }
    __syncthreads();

    f32x4 accs[4][2];
    #pragma unroll
    for (int ch = 0; ch < 4; ++ch) {
        FU hf[4];
        const float* hrow = &hs[(ch * 16 + l16) * 132 + quad * 8];
        #pragma unroll
        for (int kk = 0; kk < 4; ++kk) {
            float4 v0 = *(const float4*)(hrow + kk * 32);
            float4 v1 = *(const float4*)(hrow + kk * 32 + 4);
            hf[kk].u[0] = pack2_f16(v0.x, v0.y);
            hf[kk].u[1] = pack2_f16(v0.z, v0.w);
            hf[kk].u[2] = pack2_f16(v1.x, v1.y);
            hf[kk].u[3] = pack2_f16(v1.z, v1.w);
        }
        #pragma unroll
        for (int nt = 0; nt < 2; ++nt) {
            f32x4 acc = (f32x4){0.f, 0.f, 0.f, 0.f};
            #pragma unroll
            for (int kk = 0; kk < 4; ++kk)
                acc = __builtin_amdgcn_mfma_f32_16x16x32_f16(wf[nt][kk].v, hf[kk].v, acc, 0, 0, 0);
            accs[ch][nt] = acc;
        }
    }

    __syncthreads();   // all hidden LDS reads done; overlay f16 X slab

    // dump accs (+bias, f16) into [row 64][hloc 128] slab, stride 136
    #pragma unroll
    for (int ch = 0; ch < 4; ++ch) {
        #pragma unroll
        for (int nt = 0; nt < 2; ++nt) {
            uint2 o;
            o.x = pack2_f16(accs[ch][nt][0] + bh[nt][0], accs[ch][nt][1] + bh[nt][1]);
            o.y = pack2_f16(accs[ch][nt][2] + bh[nt][2], accs[ch][nt][3] + bh[nt][3]);
            *(uint2*)&xs[(ch * 16 + l16) * XS_STRIDE + (2 * waveId + nt) * 16 + quad * 4] = o;
        }
    }

    __syncthreads();

    // coalesced readout: 1024 b128 chunks; lane i -> 16B, 256B/row segments
    f16* xdst = Xout + half * (8192 * 256) + row0 * 256 + hbase;
    #pragma unroll
    for (int it = 0; it < 4; ++it) {
        int idx = it * 256 + tid;       // 0..1023
        int row = idx >> 4;
        int h8 = idx & 15;
        uint4 v = *(const uint4*)&xs[row * XS_STRIDE + h8 * 8];
        *(uint4*)&xdst[row * 256 + h8 * 8] = v;
    }
}

// ---------------- fused GEMM2 (MFMA, fp16) + MFMA payoff ----------------
// block = 512 thr = 8 waves; each wave owns 8 pairs; 64 pairs/block;
// grid 1984 XCD-swizzled. W2 staged ONCE (full 50.7 KB image, async
// global_load_lds); K-loop has ZERO internal barriers; DEPTH-4 X prefetch
// (kk 0-3 issued before the stage barrier, kk 4-7 issued 4 iters ahead).
__global__ __launch_bounds__(512, 6) void gemm_payoff_kernel(
    const f16* __restrict__ X1, const f16* __restrict__ X2,
    const int* __restrict__ e_f, const int* __restrict__ e_t,
    const f16* __restrict__ w2g, const float* __restrict__ b2,
    float* __restrict__ out) {

    __shared__ __align__(16) unsigned char smem[LDS_BYTES];
    f16* w2s = (f16*)smem;

    const int tid = threadIdx.x;
    const int ln = tid & 63;
    const int waveId = tid >> 6;
    const int quad = ln >> 4;
    const int l16 = ln & 15;
    const int pl = l16 & 7;
    const int s = l16 >> 3;

    // XCD swizzle: 1984 = 8 * 248 (bijective)
    const int bx = blockIdx.x;
    const int lb = (bx & 7) * 248 + (bx >> 3);

    // stage full W2 image once: 51 x 1KB async chunks, wave-strided
    {
        const unsigned char* src = (const unsigned char*)w2g + ln * 16;
        #pragma unroll
        for (int j = 0; j < 7; ++j) {
            int i = waveId + j * 8;
            if (i < W2_CHUNKS)
                load_lds16(src + i * 1024, smem + i * 1024);
        }
    }

    // edge dtype detect (uniform -> scalar loads)
    bool f64 = true, t64 = true;
    #pragma unroll
    for (int i = 0; i < 16; ++i) {
        if (e_f[2 * i + 1] != 0) f64 = false;
        if (e_t[2 * i + 1] != 0) t64 = false;
    }

    const int pairBase = lb * 64 + waveId * 8;
    const f16* px1;
    const f16* px2;
    {
        int pair = pairBase + pl;
        int b = pair / E_CNT;
        int e = pair - b * E_CNT;
        int f = f64 ? e_f[2 * e] : e_f[e];
        int t = t64 ? e_t[2 * e] : e_t[e];
        int n1 = s ? t : f;
        int n2 = s ? f : t;
        px1 = X1 + ((b * 32 + n1) * 256 + quad * 8);
        px2 = X2 + ((b * 32 + n2) * 256 + quad * 8);
    }

    f32x4 acc[6];
    #pragma unroll
    for (int tt = 0; tt < 6; ++tt) acc[tt] = (f32x4){0.f, 0.f, 0.f, 0.f};

    typedef union { uint4 q; f16x8 h; } XU;
    XU G1[4], G2[4];
    #pragma unroll
    for (int c = 0; c < 4; ++c) {
        G1[c].q = *(const uint4*)(px1 + c * 32);
        G2[c].q = *(const uint4*)(px2 + c * 32);
    }

    const f16x8 zero8 = (f16x8){0, 0, 0, 0, 0, 0, 0, 0};

    __syncthreads();   // W2 fully staged; kk 0-3 load latency hidden under stage

    // all 8 kk, no internal barriers; depth-4 circular X prefetch
    #pragma unroll
    for (int kk = 0; kk < 8; ++kk) {
        const int buf = kk & 3;
        f16x8 sum = G1[buf].h + G2[buf].h;
        f16x8 af = __builtin_elementwise_max(sum, zero8);
        if (kk < 4) {
            G1[buf].q = *(const uint4*)(px1 + (kk + 4) * 32);
            G2[buf].q = *(const uint4*)(px2 + (kk + 4) * 32);
        }
        #pragma unroll
        for (int tt = 0; tt < 6; ++tt) {
            f16x8 bf = *(const f16x8*)&w2s[(tt * 16 + l16) * W2_STRIDE + kk * 32 + quad * 8];
            acc[tt] = __builtin_amdgcn_mfma_f32_16x16x32_f16(af, bf, acc[tt], 0, 0, 0);
        }
    }

    // epilogue precompute AFTER the K-loop (keeps K-loop peak registers low)
    float b2v[6];
    #pragma unroll
    for (int tt = 0; tt < 6; ++tt) b2v[tt] = b2[tt * 16 + l16];

    int d6[6];
    float psc[6];
    {
        const int s_ = quad >> 1;
        #pragma unroll
        for (int tt = 0; tt < 6; ++tt) {
            int n = tt * 16 + l16;
            int rr = n / 24;
            int rem = n - rr * 24;
            int c01 = (rem >= 12) ? 1 : 0;
            int a = rem - c01 * 12;
            int k8 = s_ * 4 + rr;
            int toL = (c01 == s_) ? 1 : 0;
            d6[tt] = (toL ? 0 : V_OFF) + (quad & 1) * 4 * PP_STRIDE + a * 8 + k8;
            psc[tt] = toL ? 0.5f : 1.0f;   // fold the 0.5 into the U (left) side
        }
    }

    __syncthreads();   // all waves done reading W2; overlay per-wave payoff regions

    f16* pm = (f16*)smem + waveId * PW_F16;

    // dump p (+b2, x psc) as f16 into [side][pp][i*8+k8], pp-stride 136
    #pragma unroll
    for (int tt = 0; tt < 6; ++tt) {
        #pragma unroll
        for (int r = 0; r < 4; ++r)
            pm[d6[tt] + r * PP_STRIDE] = (_Float16)((acc[tt][r] + b2v[tt]) * psc[tt]);
    }

    // payoff: one MFMA per pair, A = V (j rows), B = U (i rows)
    // -> D[col=l16=i][row=quad*4+r=j] -> coalesced float4 stores
    #pragma unroll
    for (int pp = 0; pp < 8; ++pp) {
        f16x8 afp = zero8, bfp = zero8;
        if (quad == 0) {
            afp = *(const f16x8*)&pm[V_OFF + pp * PP_STRIDE + l16 * 8];
            bfp = *(const f16x8*)&pm[pp * PP_STRIDE + l16 * 8];
        }
        f32x4 d = __builtin_amdgcn_mfma_f32_16x16x32_f16(
            afp, bfp, (f32x4){0.f, 0.f, 0.f, 0.f}, 0, 0, 0);
        if (l16 < 12 && quad < 3) {
            float* ob = out + (pairBase + pp) * 144 + l16 * 12 + quad * 4;
            *(float4*)ob = make_float4(d[0], d[1], d[2], d[3]);
        }
    }
}

extern "C" void kernel_launch(void* const* d_in, const int* in_sizes, int n_in,
                              void* d_out, int out_size, void* d_ws, size_t ws_size,
                              hipStream_t stream) {
    const float* hidden = (const float*)d_in[0];
    const float* W1 = (const float*)d_in[1];
    const float* b1 = (const float*)d_in[2];
    const float* W2 = (const float*)d_in[3];
    const float* b2 = (const float*)d_in[4];
    const int* e_f = (const int*)d_in[5];
    const int* e_t = (const int*)d_in[6];
    float* out = (float*)d_out;

    char* ws = (char*)d_ws;
    f16* X = (f16*)ws;                              // X1 then X2, 4 MB each
    f16* w2h = (f16*)(ws + 8 * 1024 * 1024);        // W2 f16 image [96][264] + stage slop

    x_kernel<<<513, 256, 0, stream>>>(hidden, W1, b1, X, W2, w2h);
    gemm_payoff_kernel<<<1984, 512, 0, stream>>>(X, X + 8192 * 256, e_f, e_t, w2h, b2, out);
}

// Round 8
// 131.144 us; speedup vs baseline: 1.0200x; 1.0081x over previous
//
#include <hip/hip_runtime.h>

typedef unsigned int uint;
typedef _Float16 f16;

typedef __attribute__((ext_vector_type(8))) _Float16 f16x8;
typedef __attribute__((ext_vector_type(2))) _Float16 f16x2;
typedef __attribute__((ext_vector_type(4))) float f32x4;
typedef __attribute__((ext_vector_type(16))) float f32x16;

#define E_CNT 496

// W2 f16 image: [96][264] f16 = 50688 B (stride 264 f16 = 132 dwords).
#define W2_STRIDE 264
#define W2_STAGE_BYTES 52224             // 51 x 1024
#define W2_CHUNKS 51
#define LDS_BYTES 53248                  // max(stage 52224, payoff 8*6656)

// payoff per-wave overlay: [2 sides][16 pp][104 f16] = 3328 f16 = 6656 B
#define PP_STRIDE 104
#define V_OFF 1664
#define PW_BYTES 6656

// x_kernel LDS: hidden [64][132] f32 (33792 B) + X slab [64][264] f16 (33792 B)
#define XS_STRIDE 264
#define XH_BYTES 33792

__device__ __forceinline__ uint pack2_f16(float lo, float hi) {
    union { f16x2 h; uint u; } r;
    r.h[0] = (_Float16)lo;
    r.h[1] = (_Float16)hi;
    return r.u;
}

__device__ __forceinline__ void load_lds16(const void* g, void* l) {
    __builtin_amdgcn_global_load_lds(
        (const __attribute__((address_space(1))) void*)g,
        (__attribute__((address_space(3))) void*)l, 16, 0, 0);
}

// ---------------- X staging via swapped-operand MFMA ----------------
// grid = 257; blocks 0..255 = 128 rowblocks x 2 halves; block 256 converts W2.
// Block covers the FULL 256-col half for 64 rows in 2 register passes;
// hidden staged once (2x dedup vs 4x before); X stores 512 B/row coalesced.
__global__ __launch_bounds__(256) void x_kernel(
    const float* __restrict__ hidden, const float* __restrict__ W1,
    const float* __restrict__ b1, f16* __restrict__ Xout,
    const float* __restrict__ W2, f16* __restrict__ w2h) {
    __shared__ __align__(16) unsigned char xsmem[XH_BYTES + 64 * XS_STRIDE * 2];
    float* hs = (float*)xsmem;                    // hidden [64][132] f32
    f16* xs = (f16*)(xsmem + XH_BYTES);           // X slab [64][264] f16

    const int tid = threadIdx.x;

    if (blockIdx.x == 256) {
        // convert W2 f32 [96][256] -> f16 image [96][264] (pad never read)
        #pragma unroll
        for (int j = 0; j < 24; ++j) {
            int idx4 = tid + j * 256;
            int n = idx4 >> 6;
            int k = (idx4 & 63) << 2;
            float4 v = *(const float4*)&W2[n * 256 + k];
            uint2 o;
            o.x = pack2_f16(v.x, v.y);
            o.y = pack2_f16(v.z, v.w);
            *(uint2*)&w2h[n * W2_STRIDE + k] = o;
        }
        return;
    }

    const int rowblock = blockIdx.x >> 1;
    const int half = blockIdx.x & 1;
    const int ln = tid & 63;
    const int waveId = tid >> 6;
    const int quad = ln >> 4;
    const int l16 = ln & 15;
    const int row0 = rowblock * 64;

    // stage 64 hidden rows (coalesced float4)
    {
        const float* src = hidden + row0 * 128;
        #pragma unroll
        for (int it = 0; it < 8; ++it) {
            int idx = it * 256 + tid;
            int r = idx >> 5;
            int c4 = idx & 31;
            float4 v = *(const float4*)(src + idx * 4);
            *(float4*)&hs[r * 132 + c4 * 4] = v;
        }
    }
    __syncthreads();

    union FU { uint u[4]; f16x8 v; };

    #pragma unroll
    for (int p = 0; p < 2; ++p) {
        // W1 frags for this pass's 2 n-tiles
        FU wf[2][4];
        float bh[2][4];
        #pragma unroll
        for (int nt = 0; nt < 2; ++nt) {
            const int tl = p * 8 + waveId * 2 + nt;   // htile 0..15 within half
            const float* wrow = W1 + (tl * 16 + l16) * 256 + half * 128 + quad * 8;
            #pragma unroll
            for (int kk = 0; kk < 4; ++kk) {
                float4 v0 = *(const float4*)(wrow + kk * 32);
                float4 v1 = *(const float4*)(wrow + kk * 32 + 4);
                wf[nt][kk].u[0] = pack2_f16(v0.x, v0.y);
                wf[nt][kk].u[1] = pack2_f16(v0.z, v0.w);
                wf[nt][kk].u[2] = pack2_f16(v1.x, v1.y);
                wf[nt][kk].u[3] = pack2_f16(v1.z, v1.w);
            }
            #pragma unroll
            for (int r = 0; r < 4; ++r)
                bh[nt][r] = 0.5f * b1[tl * 16 + quad * 4 + r];
        }

        #pragma unroll
        for (int ch = 0; ch < 4; ++ch) {
            FU hf[4];
            const float* hrow = &hs[(ch * 16 + l16) * 132 + quad * 8];
            #pragma unroll
            for (int kk = 0; kk < 4; ++kk) {
                float4 v0 = *(const float4*)(hrow + kk * 32);
                float4 v1 = *(const float4*)(hrow + kk * 32 + 4);
                hf[kk].u[0] = pack2_f16(v0.x, v0.y);
                hf[kk].u[1] = pack2_f16(v0.z, v0.w);
                hf[kk].u[2] = pack2_f16(v1.x, v1.y);
                hf[kk].u[3] = pack2_f16(v1.z, v1.w);
            }
            #pragma unroll
            for (int nt = 0; nt < 2; ++nt) {
                const int tl = p * 8 + waveId * 2 + nt;
                f32x4 acc = (f32x4){0.f, 0.f, 0.f, 0.f};
                #pragma unroll
                for (int kk = 0; kk < 4; ++kk)
                    acc = __builtin_amdgcn_mfma_f32_16x16x32_f16(wf[nt][kk].v, hf[kk].v, acc, 0, 0, 0);
                uint2 o;
                o.x = pack2_f16(acc[0] + bh[nt][0], acc[1] + bh[nt][1]);
                o.y = pack2_f16(acc[2] + bh[nt][2], acc[3] + bh[nt][3]);
                *(uint2*)&xs[(ch * 16 + l16) * XS_STRIDE + tl * 16 + quad * 4] = o;
            }
        }
    }

    __syncthreads();

    // coalesced readout: 2048 x 16B; 512 B contiguous per row
    f16* xdst = Xout + half * (8192 * 256) + row0 * 256;
    #pragma unroll
    for (int it = 0; it < 8; ++it) {
        int idx = it * 256 + tid;       // 0..2047
        int row = idx >> 5;
        int c8 = idx & 31;
        uint4 v = *(const uint4*)&xs[row * XS_STRIDE + c8 * 8];
        *(uint4*)&xdst[row * 256 + c8 * 8] = v;
    }
}

// ---------------- fused GEMM2 (32x32x16 MFMA) + MFMA payoff ----------------
// block = 512 thr = 8 waves; each wave owns 16 pairs (M=32 rows: 16 pairs x
// 2 sides); 128 pairs/block; grid 992 XCD-swizzled. W2 staged ONCE; K-loop:
// 16 kk x (3 ds_read + 3 MFMA), zero internal barriers, depth-4 X prefetch.
__global__ __launch_bounds__(512) void gemm_payoff_kernel(
    const f16* __restrict__ X1, const f16* __restrict__ X2,
    const int* __restrict__ e_f, const int* __restrict__ e_t,
    const f16* __restrict__ w2g, const float* __restrict__ b2,
    float* __restrict__ out) {

    __shared__ __align__(16) unsigned char smem[LDS_BYTES];
    f16* w2s = (f16*)smem;

    const int tid = threadIdx.x;
    const int ln = tid & 63;
    const int waveId = tid >> 6;
    const int l32 = ln & 31;
    const int khalf = ln >> 5;
    const int quad = ln >> 4;      // 16x16 decomposition (payoff)
    const int l16 = ln & 15;

    // XCD swizzle: 992 = 8 * 124 (bijective)
    const int bx = blockIdx.x;
    const int lb = (bx & 7) * 124 + (bx >> 3);

    // stage full W2 image once: 51 x 1KB async chunks, wave-strided
    {
        const unsigned char* src = (const unsigned char*)w2g + ln * 16;
        #pragma unroll
        for (int j = 0; j < 7; ++j) {
            int i = waveId + j * 8;
            if (i < W2_CHUNKS)
                load_lds16(src + i * 1024, smem + i * 1024);
        }
    }

    // edge dtype detect (uniform -> scalar loads)
    bool f64 = true, t64 = true;
    #pragma unroll
    for (int i = 0; i < 16; ++i) {
        if (e_f[2 * i + 1] != 0) f64 = false;
        if (e_t[2 * i + 1] != 0) t64 = false;
    }

    const int pairBase = lb * 128 + waveId * 16;
    const f16* px1;
    const f16* px2;
    {
        int p = ln & 15;                 // pair within wave (A row & 15)
        int sdim = (ln >> 4) & 1;        // side (A row >> 4)
        int pair = pairBase + p;
        int b = pair / E_CNT;
        int e = pair - b * E_CNT;
        int f = f64 ? e_f[2 * e] : e_f[e];
        int t = t64 ? e_t[2 * e] : e_t[e];
        int n1 = sdim ? t : f;
        int n2 = sdim ? f : t;
        px1 = X1 + ((b * 32 + n1) * 256 + khalf * 8);
        px2 = X2 + ((b * 32 + n2) * 256 + khalf * 8);
    }

    f32x16 acc[3];
    #pragma unroll
    for (int tt = 0; tt < 3; ++tt)
        #pragma unroll
        for (int j = 0; j < 16; ++j) acc[tt][j] = 0.f;

    typedef union { uint4 q; f16x8 h; } XU;
    XU G1[4], G2[4];
    #pragma unroll
    for (int c = 0; c < 4; ++c) {
        G1[c].q = *(const uint4*)(px1 + c * 16);
        G2[c].q = *(const uint4*)(px2 + c * 16);
    }

    const f16x8 zero8 = (f16x8){0, 0, 0, 0, 0, 0, 0, 0};

    __syncthreads();   // W2 fully staged; kk 0-3 latency hidden under stage

    // 16 kk steps, no internal barriers; depth-4 circular X prefetch
    #pragma unroll
    for (int kk = 0; kk < 16; ++kk) {
        const int buf = kk & 3;
        f16x8 sum = G1[buf].h + G2[buf].h;
        f16x8 af = __builtin_elementwise_max(sum, zero8);
        if (kk < 12) {
            G1[buf].q = *(const uint4*)(px1 + (kk + 4) * 16);
            G2[buf].q = *(const uint4*)(px2 + (kk + 4) * 16);
        }
        #pragma unroll
        for (int tt = 0; tt < 3; ++tt) {
            f16x8 bf = *(const f16x8*)&w2s[(tt * 32 + l32) * W2_STRIDE + kk * 16 + khalf * 8];
            acc[tt] = __builtin_amdgcn_mfma_f32_32x32x16_f16(af, bf, acc[tt], 0, 0, 0);
        }
    }

    // epilogue precompute (after K-loop to keep hot-loop registers low)
    // per tt: n = tt*32 + l32 -> (rr, c01, a); two dest groups by s_row = j>>3
    float b2n[3];
    int d0[3], d1[3];
    float sc0[3], sc1[3];
    #pragma unroll
    for (int tt = 0; tt < 3; ++tt) {
        int n = tt * 32 + l32;
        b2n[tt] = b2[n];
        int rr = n / 24;
        int rem = n - rr * 24;
        int c01 = (rem >= 12) ? 1 : 0;
        int a = rem - c01 * 12;
        int toL0 = (c01 == 0);
        int toL1 = (c01 == 1);
        d0[tt] = (toL0 ? 0 : V_OFF) + a * 8 + rr;        // s_row=0: k8=rr
        d1[tt] = (toL1 ? 0 : V_OFF) + a * 8 + 4 + rr;    // s_row=1: k8=4+rr
        sc0[tt] = toL0 ? 0.5f : 1.0f;
        sc1[tt] = toL1 ? 0.5f : 1.0f;
    }

    __syncthreads();   // all waves done reading W2; overlay per-wave payoff regions

    f16* pm = (f16*)(smem + waveId * PW_BYTES);

    // dump p (+b2, x sc) as f16 into [side][pp 0..15][a*8+k8], pp-stride 104
    // D layout: col = l32 (n), row = (j&3) + 8*(j>>2) + 4*khalf
    #pragma unroll
    for (int tt = 0; tt < 3; ++tt) {
        #pragma unroll
        for (int j = 0; j < 16; ++j) {
            int pp = (j & 3) + 8 * ((j >> 2) & 1) + 4 * khalf;
            int dst = ((j >> 3) ? d1[tt] : d0[tt]) + pp * PP_STRIDE;
            float sc = (j >> 3) ? sc1[tt] : sc0[tt];
            pm[dst] = (_Float16)((acc[tt][j] + b2n[tt]) * sc);
        }
    }

    // payoff: one 16x16x32 MFMA per pair (K=8 in quad 0)
    // A = R rows (j), B = L rows (i) -> D[col=l16=i][row=quad*4+r=j]
    #pragma unroll
    for (int pp = 0; pp < 16; ++pp) {
        f16x8 afp = zero8, bfp = zero8;
        if (quad == 0) {
            afp = *(const f16x8*)&pm[V_OFF + pp * PP_STRIDE + l16 * 8];
            bfp = *(const f16x8*)&pm[pp * PP_STRIDE + l16 * 8];
        }
        f32x4 d = __builtin_amdgcn_mfma_f32_16x16x32_f16(
            afp, bfp, (f32x4){0.f, 0.f, 0.f, 0.f}, 0, 0, 0);
        if (l16 < 12 && quad < 3) {
            float* ob = out + (pairBase + pp) * 144 + l16 * 12 + quad * 4;
            *(float4*)ob = make_float4(d[0], d[1], d[2], d[3]);
        }
    }
}

extern "C" void kernel_launch(void* const* d_in, const int* in_sizes, int n_in,
                              void* d_out, int out_size, void* d_ws, size_t ws_size,
                              hipStream_t stream) {
    const float* hidden = (const float*)d_in[0];
    const float* W1 = (const float*)d_in[1];
    const float* b1 = (const float*)d_in[2];
    const float* W2 = (const float*)d_in[3];
    const float* b2 = (const float*)d_in[4];
    const int* e_f = (const int*)d_in[5];
    const int* e_t = (const int*)d_in[6];
    float* out = (float*)d_out;

    char* ws = (char*)d_ws;
    f16* X = (f16*)ws;                              // X1 then X2, 4 MB each
    f16* w2h = (f16*)(ws + 8 * 1024 * 1024);        // W2 f16 image [96][264] + stage slop

    x_kernel<<<257, 256, 0, stream>>>(hidden, W1, b1, X, W2, w2h);
    gemm_payoff_kernel<<<992, 512, 0, stream>>>(X, X + 8192 * 256, e_f, e_t, w2h, b2, out);
}

// Round 9
// 130.671 us; speedup vs baseline: 1.0237x; 1.0036x over previous
//
#include <hip/hip_runtime.h>

typedef unsigned int uint;
typedef _Float16 f16;

typedef __attribute__((ext_vector_type(8))) _Float16 f16x8;
typedef __attribute__((ext_vector_type(2))) _Float16 f16x2;
typedef __attribute__((ext_vector_type(4))) float f32x4;

#define E_CNT 496

// W2 f16 image: [96][264] f16 = 50688 B (stride 264 f16 = 132 dwords).
#define W2_STRIDE 264
#define W2_STAGE_BYTES 52224             // 51 x 1024
#define W2_CHUNKS 51
#define LDS_BYTES 52224

// payoff per-wave overlay region: [2 sides][8 pp][136 f16] = 2176 f16 = 4352 B
#define PP_STRIDE 136
#define V_OFF 1088
#define PW_F16 2176

// x_kernel LDS: hidden [64][132] f32 (33792 B) + X slab [64][264] f16 (33792 B)
#define XS_STRIDE 264
#define XH_BYTES 33792

__device__ __forceinline__ uint pack2_f16(float lo, float hi) {
    union { f16x2 h; uint u; } r;
    r.h[0] = (_Float16)lo;
    r.h[1] = (_Float16)hi;
    return r.u;
}

__device__ __forceinline__ void load_lds16(const void* g, void* l) {
    __builtin_amdgcn_global_load_lds(
        (const __attribute__((address_space(1))) void*)g,
        (__attribute__((address_space(3))) void*)l, 16, 0, 0);
}

// ---------------- X staging via swapped-operand MFMA (R8 structure) --------
// grid = 257; blocks 0..255 = 128 rowblocks x 2 halves; block 256 converts W2.
// Block covers the FULL 256-col half for 64 rows in 2 register passes;
// hidden staged once (2x dedup); X stores 512 B/row coalesced.
__global__ __launch_bounds__(256) void x_kernel(
    const float* __restrict__ hidden, const float* __restrict__ W1,
    const float* __restrict__ b1, f16* __restrict__ Xout,
    const float* __restrict__ W2, f16* __restrict__ w2h) {
    __shared__ __align__(16) unsigned char xsmem[XH_BYTES + 64 * XS_STRIDE * 2];
    float* hs = (float*)xsmem;                    // hidden [64][132] f32
    f16* xs = (f16*)(xsmem + XH_BYTES);           // X slab [64][264] f16

    const int tid = threadIdx.x;

    if (blockIdx.x == 256) {
        // convert W2 f32 [96][256] -> f16 image [96][264] (pad never read)
        #pragma unroll
        for (int j = 0; j < 24; ++j) {
            int idx4 = tid + j * 256;
            int n = idx4 >> 6;
            int k = (idx4 & 63) << 2;
            float4 v = *(const float4*)&W2[n * 256 + k];
            uint2 o;
            o.x = pack2_f16(v.x, v.y);
            o.y = pack2_f16(v.z, v.w);
            *(uint2*)&w2h[n * W2_STRIDE + k] = o;
        }
        return;
    }

    const int rowblock = blockIdx.x >> 1;
    const int half = blockIdx.x & 1;
    const int ln = tid & 63;
    const int waveId = tid >> 6;
    const int quad = ln >> 4;
    const int l16 = ln & 15;
    const int row0 = rowblock * 64;

    // stage 64 hidden rows (coalesced float4)
    {
        const float* src = hidden + row0 * 128;
        #pragma unroll
        for (int it = 0; it < 8; ++it) {
            int idx = it * 256 + tid;
            int r = idx >> 5;
            int c4 = idx & 31;
            float4 v = *(const float4*)(src + idx * 4);
            *(float4*)&hs[r * 132 + c4 * 4] = v;
        }
    }
    __syncthreads();

    union FU { uint u[4]; f16x8 v; };

    #pragma unroll
    for (int p = 0; p < 2; ++p) {
        // W1 frags for this pass's 2 n-tiles
        FU wf[2][4];
        float bh[2][4];
        #pragma unroll
        for (int nt = 0; nt < 2; ++nt) {
            const int tl = p * 8 + waveId * 2 + nt;   // htile 0..15 within half
            const float* wrow = W1 + (tl * 16 + l16) * 256 + half * 128 + quad * 8;
            #pragma unroll
            for (int kk = 0; kk < 4; ++kk) {
                float4 v0 = *(const float4*)(wrow + kk * 32);
                float4 v1 = *(const float4*)(wrow + kk * 32 + 4);
                wf[nt][kk].u[0] = pack2_f16(v0.x, v0.y);
                wf[nt][kk].u[1] = pack2_f16(v0.z, v0.w);
                wf[nt][kk].u[2] = pack2_f16(v1.x, v1.y);
                wf[nt][kk].u[3] = pack2_f16(v1.z, v1.w);
            }
            #pragma unroll
            for (int r = 0; r < 4; ++r)
                bh[nt][r] = 0.5f * b1[tl * 16 + quad * 4 + r];
        }

        #pragma unroll
        for (int ch = 0; ch < 4; ++ch) {
            FU hf[4];
            const float* hrow = &hs[(ch * 16 + l16) * 132 + quad * 8];
            #pragma unroll
            for (int kk = 0; kk < 4; ++kk) {
                float4 v0 = *(const float4*)(hrow + kk * 32);
                float4 v1 = *(const float4*)(hrow + kk * 32 + 4);
                hf[kk].u[0] = pack2_f16(v0.x, v0.y);
                hf[kk].u[1] = pack2_f16(v0.z, v0.w);
                hf[kk].u[2] = pack2_f16(v1.x, v1.y);
                hf[kk].u[3] = pack2_f16(v1.z, v1.w);
            }
            #pragma unroll
            for (int nt = 0; nt < 2; ++nt) {
                const int tl = p * 8 + waveId * 2 + nt;
                f32x4 acc = (f32x4){0.f, 0.f, 0.f, 0.f};
                #pragma unroll
                for (int kk = 0; kk < 4; ++kk)
                    acc = __builtin_amdgcn_mfma_f32_16x16x32_f16(wf[nt][kk].v, hf[kk].v, acc, 0, 0, 0);
                uint2 o;
                o.x = pack2_f16(acc[0] + bh[nt][0], acc[1] + bh[nt][1]);
                o.y = pack2_f16(acc[2] + bh[nt][2], acc[3] + bh[nt][3]);
                *(uint2*)&xs[(ch * 16 + l16) * XS_STRIDE + tl * 16 + quad * 4] = o;
            }
        }
    }

    __syncthreads();

    // coalesced readout: 2048 x 16B; 512 B contiguous per row
    f16* xdst = Xout + half * (8192 * 256) + row0 * 256;
    #pragma unroll
    for (int it = 0; it < 8; ++it) {
        int idx = it * 256 + tid;       // 0..2047
        int row = idx >> 5;
        int c8 = idx & 31;
        uint4 v = *(const uint4*)&xs[row * XS_STRIDE + c8 * 8];
        *(uint4*)&xdst[row * 256 + c8 * 8] = v;
    }
}

// ---------------- fused GEMM2 (MFMA, fp16) + MFMA payoff (R6 structure) ----
// block = 512 thr = 8 waves; each wave owns 8 pairs; 64 pairs/block;
// grid 1984 XCD-swizzled. W2 staged ONCE (full 50.7 KB image, async
// global_load_lds); K-loop has ZERO internal barriers; DEPTH-4 X prefetch
// (kk 0-3 issued before the stage barrier, kk 4-7 issued 4 iters ahead).
__global__ __launch_bounds__(512, 6) void gemm_payoff_kernel(
    const f16* __restrict__ X1, const f16* __restrict__ X2,
    const int* __restrict__ e_f, const int* __restrict__ e_t,
    const f16* __restrict__ w2g, const float* __restrict__ b2,
    float* __restrict__ out) {

    __shared__ __align__(16) unsigned char smem[LDS_BYTES];
    f16* w2s = (f16*)smem;

    const int tid = threadIdx.x;
    const int ln = tid & 63;
    const int waveId = tid >> 6;
    const int quad = ln >> 4;
    const int l16 = ln & 15;
    const int pl = l16 & 7;
    const int s = l16 >> 3;

    // XCD swizzle: 1984 = 8 * 248 (bijective)
    const int bx = blockIdx.x;
    const int lb = (bx & 7) * 248 + (bx >> 3);

    // stage full W2 image once: 51 x 1KB async chunks, wave-strided
    {
        const unsigned char* src = (const unsigned char*)w2g + ln * 16;
        #pragma unroll
        for (int j = 0; j < 7; ++j) {
            int i = waveId + j * 8;
            if (i < W2_CHUNKS)
                load_lds16(src + i * 1024, smem + i * 1024);
        }
    }

    // edge dtype detect (uniform -> scalar loads)
    bool f64 = true, t64 = true;
    #pragma unroll
    for (int i = 0; i < 16; ++i) {
        if (e_f[2 * i + 1] != 0) f64 = false;
        if (e_t[2 * i + 1] != 0) t64 = false;
    }

    const int pairBase = lb * 64 + waveId * 8;
    const f16* px1;
    const f16* px2;
    {
        int pair = pairBase + pl;
        int b = pair / E_CNT;
        int e = pair - b * E_CNT;
        int f = f64 ? e_f[2 * e] : e_f[e];
        int t = t64 ? e_t[2 * e] : e_t[e];
        int n1 = s ? t : f;
        int n2 = s ? f : t;
        px1 = X1 + ((b * 32 + n1) * 256 + quad * 8);
        px2 = X2 + ((b * 32 + n2) * 256 + quad * 8);
    }

    f32x4 acc[6];
    #pragma unroll
    for (int tt = 0; tt < 6; ++tt) acc[tt] = (f32x4){0.f, 0.f, 0.f, 0.f};

    typedef union { uint4 q; f16x8 h; } XU;
    XU G1[4], G2[4];
    #pragma unroll
    for (int c = 0; c < 4; ++c) {
        G1[c].q = *(const uint4*)(px1 + c * 32);
        G2[c].q = *(const uint4*)(px2 + c * 32);
    }

    const f16x8 zero8 = (f16x8){0, 0, 0, 0, 0, 0, 0, 0};

    __syncthreads();   // W2 fully staged; kk 0-3 load latency hidden under stage

    // all 8 kk, no internal barriers; depth-4 circular X prefetch
    #pragma unroll
    for (int kk = 0; kk < 8; ++kk) {
        const int buf = kk & 3;
        f16x8 sum = G1[buf].h + G2[buf].h;
        f16x8 af = __builtin_elementwise_max(sum, zero8);
        if (kk < 4) {
            G1[buf].q = *(const uint4*)(px1 + (kk + 4) * 32);
            G2[buf].q = *(const uint4*)(px2 + (kk + 4) * 32);
        }
        #pragma unroll
        for (int tt = 0; tt < 6; ++tt) {
            f16x8 bf = *(const f16x8*)&w2s[(tt * 16 + l16) * W2_STRIDE + kk * 32 + quad * 8];
            acc[tt] = __builtin_amdgcn_mfma_f32_16x16x32_f16(af, bf, acc[tt], 0, 0, 0);
        }
    }

    // epilogue precompute AFTER the K-loop (keeps K-loop peak registers low)
    float b2v[6];
    #pragma unroll
    for (int tt = 0; tt < 6; ++tt) b2v[tt] = b2[tt * 16 + l16];

    int d6[6];
    float psc[6];
    {
        const int s_ = quad >> 1;
        #pragma unroll
        for (int tt = 0; tt < 6; ++tt) {
            int n = tt * 16 + l16;
            int rr = n / 24;
            int rem = n - rr * 24;
            int c01 = (rem >= 12) ? 1 : 0;
            int a = rem - c01 * 12;
            int k8 = s_ * 4 + rr;
            int toL = (c01 == s_) ? 1 : 0;
            d6[tt] = (toL ? 0 : V_OFF) + (quad & 1) * 4 * PP_STRIDE + a * 8 + k8;
            psc[tt] = toL ? 0.5f : 1.0f;   // fold the 0.5 into the U (left) side
        }
    }

    __syncthreads();   // all waves done reading W2; overlay per-wave payoff regions

    f16* pm = (f16*)smem + waveId * PW_F16;

    // dump p (+b2, x psc) as f16 into [side][pp][i*8+k8], pp-stride 136
    #pragma unroll
    for (int tt = 0; tt < 6; ++tt) {
        #pragma unroll
        for (int r = 0; r < 4; ++r)
            pm[d6[tt] + r * PP_STRIDE] = (_Float16)((acc[tt][r] + b2v[tt]) * psc[tt]);
    }

    // payoff: one MFMA per pair, A = V (j rows), B = U (i rows)
    // -> D[col=l16=i][row=quad*4+r=j] -> coalesced float4 stores
    #pragma unroll
    for (int pp = 0; pp < 8; ++pp) {
        f16x8 afp = zero8, bfp = zero8;
        if (quad == 0) {
            afp = *(const f16x8*)&pm[V_OFF + pp * PP_STRIDE + l16 * 8];
            bfp = *(const f16x8*)&pm[pp * PP_STRIDE + l16 * 8];
        }
        f32x4 d = __builtin_amdgcn_mfma_f32_16x16x32_f16(
            afp, bfp, (f32x4){0.f, 0.f, 0.f, 0.f}, 0, 0, 0);
        if (l16 < 12 && quad < 3) {
            float* ob = out + (pairBase + pp) * 144 + l16 * 12 + quad * 4;
            *(float4*)ob = make_float4(d[0], d[1], d[2], d[3]);
        }
    }
}

extern "C" void kernel_launch(void* const* d_in, const int* in_sizes, int n_in,
                              void* d_out, int out_size, void* d_ws, size_t ws_size,
                              hipStream_t stream) {
    const float* hidden = (const float*)d_in[0];
    const float* W1 = (const float*)d_in[1];
    const float* b1 = (const float*)d_in[2];
    const float* W2 = (const float*)d_in[3];
    const float* b2 = (const float*)d_in[4];
    const int* e_f = (const int*)d_in[5];
    const int* e_t = (const int*)d_in[6];
    float* out = (float*)d_out;

    char* ws = (char*)d_ws;
    f16* X = (f16*)ws;                              // X1 then X2, 4 MB each
    f16* w2h = (f16*)(ws + 8 * 1024 * 1024);        // W2 f16 image [96][264] + stage slop

    x_kernel<<<257, 256, 0, stream>>>(hidden, W1, b1, X, W2, w2h);
    gemm_payoff_kernel<<<1984, 512, 0, stream>>>(X, X + 8192 * 256, e_f, e_t, w2h, b2, out);
}